// Round 1
// baseline (844.514 us; speedup 1.0000x reference)
//
#include <hip/hip_runtime.h>
#include <cmath>
#include <cfloat>

#define NUM_EMB 1024
#define EMB_DIM 256
#define BATCH 32
#define SEQ 2048
#define NROWS 65536            // BATCH*SEQ
// d_out offsets (floats): [loss | quantized (b,c,l) | perplexity | encodings (N,K)]
#define Q_OFF 1
#define PERP_OFF 16777217
#define ENC_OFF 16777218
// ws offsets (bytes)
#define WS_IDX 0
#define WS_A      (NROWS * 4)
#define WS_E2     (WS_A + NROWS * 4)
#define WS_COUNTS (WS_E2 + NUM_EMB * 4)
#define WS_SSE    (WS_COUNTS + NUM_EMB * 4)

// square with a barrier so the compiler cannot contract x*x into a following add (numpy adds are plain fp32 adds)
__device__ __forceinline__ float sqg(float x) {
    float s = x * x;
    asm volatile("" : "+v"(s));
    return s;
}

// numpy pairwise sum of squares over 256 contiguous-index elements (stride in elements),
// replicating numpy's AVX512 path: 256 -> two 128-blocks; block = 8 vector accumulators
// (16 lanes) combined ((r0+r1)+(r2+r3))+((r4+r5)+(r6+r7)), then +8/+4/+2/+1 lane tree.
template <int STRIDE>
__device__ float np_sumsq256(const float* __restrict__ p) {
    float total = 0.0f;
#pragma unroll
    for (int h = 0; h < 2; ++h) {
        const int base = 128 * h;
        float c[16];
#pragma unroll
        for (int l = 0; l < 16; ++l) {
            float t0 = sqg(p[(size_t)(base + l) * STRIDE]);
            float t1 = sqg(p[(size_t)(base + 16 + l) * STRIDE]);
            float t2 = sqg(p[(size_t)(base + 32 + l) * STRIDE]);
            float t3 = sqg(p[(size_t)(base + 48 + l) * STRIDE]);
            float t4 = sqg(p[(size_t)(base + 64 + l) * STRIDE]);
            float t5 = sqg(p[(size_t)(base + 80 + l) * STRIDE]);
            float t6 = sqg(p[(size_t)(base + 96 + l) * STRIDE]);
            float t7 = sqg(p[(size_t)(base + 112 + l) * STRIDE]);
            c[l] = ((t0 + t1) + (t2 + t3)) + ((t4 + t5) + (t6 + t7));
        }
        float u[8];
#pragma unroll
        for (int l = 0; l < 8; ++l) u[l] = c[l] + c[l + 8];
        float v[4];
#pragma unroll
        for (int l = 0; l < 4; ++l) v[l] = u[l] + u[l + 4];
        float w0 = v[0] + v[2];
        float w1 = v[1] + v[3];
        // tree is l with l+8, then l+4, then l+2, then l+1:
        // after u (l,l+8) and v (l,l+4): lanes 0..3 hold {0,1,2,3}-rooted sums; combine (0,2),(1,3), then (0,1)
        float half = w0 + w1;
        total = (h == 0) ? half : (total + half);
    }
    return total;
}

__global__ void k_zero(int* __restrict__ counts) {
    int i = blockIdx.x * blockDim.x + threadIdx.x;
    if (i < NUM_EMB) counts[i] = 0;
}

__global__ void k_e2(const float* __restrict__ emb, float* __restrict__ e2) {
    int k = blockIdx.x * blockDim.x + threadIdx.x;
    if (k < NUM_EMB) e2[k] = np_sumsq256<1>(emb + (size_t)k * EMB_DIM);
}

__global__ void k_rowsum(const float* __restrict__ in, float* __restrict__ Arow) {
    int n = blockIdx.x * blockDim.x + threadIdx.x;  // 65536
    int b = n >> 11, l = n & 2047;
    Arow[n] = np_sumsq256<SEQ>(in + (size_t)b * (EMB_DIM * SEQ) + l);
}

// Main distance GEMM + argmin. 128 rows/block, 8 code-tiles of 128, d-chunks of 32.
// Per-thread 8 rows x 8 codes register tile; exact ascending-d fmaf accumulation.
__global__ __launch_bounds__(256) void k_argmin(
    const float* __restrict__ in, const float* __restrict__ emb,
    const float* __restrict__ Arow, const float* __restrict__ e2,
    int* __restrict__ idx, int* __restrict__ counts)
{
    __shared__ float Xs[32][128];    // [dd][row]
    __shared__ float Es[32][132];    // [dd][code], padded
    __shared__ float A_lds[128];
    __shared__ float redv[128][16];
    __shared__ int   redi[128][16];

    const int tid = threadIdx.x;
    const int tr = tid >> 4;   // 0..15 -> rows 8*tr..8*tr+7
    const int tc = tid & 15;   // 0..15 -> codes {4tc..4tc+3} U {64+4tc..64+4tc+3}
    const int n0 = blockIdx.x << 7;
    const int b  = n0 >> 11;
    const int l0 = n0 & 2047;
    const float* xbase = in + (size_t)b * (EMB_DIM * SEQ) + l0;

    if (tid < 128) A_lds[tid] = Arow[n0 + tid];

    float bestv[8];
    int   besti[8];
#pragma unroll
    for (int i = 0; i < 8; ++i) { bestv[i] = FLT_MAX; besti[i] = 0; }

    for (int kt = 0; kt < 8; ++kt) {
        const int k0 = kt << 7;
        float acc[8][8];
#pragma unroll
        for (int i = 0; i < 8; ++i)
#pragma unroll
            for (int j = 0; j < 8; ++j) acc[i][j] = 0.0f;

        for (int ch = 0; ch < 8; ++ch) {
            const int d0 = ch << 5;
            __syncthreads();
            {   // stage X chunk: coalesced over rows (= l)
                const int r  = tid & 127;
                const int dh = tid >> 7;
#pragma unroll
                for (int it = 0; it < 16; ++it) {
                    const int dd = (it << 1) + dh;
                    Xs[dd][r] = xbase[(size_t)(d0 + dd) * SEQ + r];
                }
            }
            {   // stage E chunk
                const int dd = tid & 31;
                const int kh = tid >> 5;
#pragma unroll
                for (int it = 0; it < 16; ++it) {
                    const int kl = (it << 3) + kh;
                    Es[dd][kl] = emb[(size_t)(k0 + kl) * EMB_DIM + d0 + dd];
                }
            }
            __syncthreads();
#pragma unroll 8
            for (int dd = 0; dd < 32; ++dd) {
                const float4 xv0 = *(const float4*)&Xs[dd][tr << 3];
                const float4 xv1 = *(const float4*)&Xs[dd][(tr << 3) + 4];
                const float4 ev0 = *(const float4*)&Es[dd][tc << 2];
                const float4 ev1 = *(const float4*)&Es[dd][64 + (tc << 2)];
                const float xs[8] = {xv0.x, xv0.y, xv0.z, xv0.w, xv1.x, xv1.y, xv1.z, xv1.w};
                const float es[8] = {ev0.x, ev0.y, ev0.z, ev0.w, ev1.x, ev1.y, ev1.z, ev1.w};
#pragma unroll
                for (int i = 0; i < 8; ++i)
#pragma unroll
                    for (int j = 0; j < 8; ++j)
                        acc[i][j] = __builtin_fmaf(xs[i], es[j], acc[i][j]);
            }
        }
        // epilogue: dist = fl(fl(A + e2) - fl(2*dot)), running argmin with first-index ties
#pragma unroll
        for (int i = 0; i < 8; ++i) {
            const int r = (tr << 3) + i;
            const float Ar = A_lds[r];
#pragma unroll
            for (int j = 0; j < 8; ++j) {
                const int kl = (j < 4) ? ((tc << 2) + j) : (64 + (tc << 2) + (j - 4));
                const int kg = k0 + kl;
                const float t = Ar + e2[kg];
                const float dist = t - 2.0f * acc[i][j];
                if (dist < bestv[i] || (dist == bestv[i] && kg < besti[i])) {
                    bestv[i] = dist;
                    besti[i] = kg;
                }
            }
        }
    }
    __syncthreads();
#pragma unroll
    for (int i = 0; i < 8; ++i) {
        redv[(tr << 3) + i][tc] = bestv[i];
        redi[(tr << 3) + i][tc] = besti[i];
    }
    __syncthreads();
    if (tid < 128) {
        float bv = redv[tid][0];
        int   bi = redi[tid][0];
#pragma unroll
        for (int j = 1; j < 16; ++j) {
            float v = redv[tid][j];
            int   ii = redi[tid][j];
            if (v < bv || (v == bv && ii < bi)) { bv = v; bi = ii; }
        }
        idx[n0 + tid] = bi;
        atomicAdd(&counts[bi], 1);
    }
}

// quantized output: out[b,c,l] = emb[idx[b*2048+l], c], via LDS transpose; fused SSE partials.
__global__ __launch_bounds__(256) void k_quant(
    const float* __restrict__ in, const float* __restrict__ emb,
    const int* __restrict__ idx, float* __restrict__ qout, double* __restrict__ ssep)
{
    __shared__ float T[256][65];
    __shared__ int lidx[64];
    __shared__ double rd[256];
    const int tid = threadIdx.x;
    const int bid = blockIdx.x;
    const int b  = bid >> 5;
    const int l0 = (bid & 31) << 6;
    const int nb = b * SEQ + l0;
    if (tid < 64) lidx[tid] = idx[nb + tid];
    __syncthreads();
#pragma unroll 4
    for (int l = 0; l < 64; ++l) {
        T[tid][l] = emb[(size_t)lidx[l] * EMB_DIM + tid];   // coalesced over c=tid
    }
    __syncthreads();
    double sse = 0.0;
    const int lo = tid & 63;
    const int ch = tid >> 6;
    for (int it = 0; it < 64; ++it) {
        const int c = (it << 2) + ch;
        const size_t g = (size_t)b * (EMB_DIM * SEQ) + (size_t)c * SEQ + l0 + lo;
        const float q = T[c][lo];
        const float x = in[g];
        qout[g] = q;
        const float d = q - x;
        sse += (double)d * (double)d;
    }
    rd[tid] = sse;
    __syncthreads();
    for (int s = 128; s > 0; s >>= 1) {
        if (tid < s) rd[tid] += rd[tid + s];
        __syncthreads();
    }
    if (tid == 0) ssep[bid] = rd[0];
}

// one-hot encodings: every element written every call (d_out is poisoned once before timing)
__global__ __launch_bounds__(256) void k_enc(const int* __restrict__ idx, float* __restrict__ enc) {
    const int gid = blockIdx.x * 256 + threadIdx.x;   // 33554432 threads, 2 floats each
    const int n  = gid >> 9;
    const int kk = (gid & 511) << 1;
    const int e = idx[n];
    float2 v;
    v.x = (e == kk) ? 1.0f : 0.0f;
    v.y = (e == kk + 1) ? 1.0f : 0.0f;
    *(float2*)(enc + (size_t)n * NUM_EMB + kk) = v;
}

__global__ __launch_bounds__(256) void k_final(const double* __restrict__ ssep,
                                               const int* __restrict__ counts,
                                               float* __restrict__ out)
{
    __shared__ double rd[256];
    const int tid = threadIdx.x;
    double s = 0.0;
    for (int i = tid; i < 1024; i += 256) s += ssep[i];
    rd[tid] = s;
    __syncthreads();
    for (int st = 128; st > 0; st >>= 1) {
        if (tid < st) rd[tid] += rd[tid + st];
        __syncthreads();
    }
    const double total = rd[0];
    __syncthreads();
    double pl = 0.0;
    for (int k = tid; k < 1024; k += 256) {
        const double p = (double)counts[k] * (1.0 / 65536.0);
        pl += p * log(p + 1e-10);
    }
    rd[tid] = pl;
    __syncthreads();
    for (int st = 128; st > 0; st >>= 1) {
        if (tid < st) rd[tid] += rd[tid + st];
        __syncthreads();
    }
    if (tid == 0) {
        out[0] = (float)(1.25 * (total * (1.0 / 16777216.0)));   // q_loss + 0.25*e_loss
        out[PERP_OFF] = (float)exp(-rd[0]);
    }
}

extern "C" void kernel_launch(void* const* d_in, const int* in_sizes, int n_in,
                              void* d_out, int out_size, void* d_ws, size_t ws_size,
                              hipStream_t stream)
{
    const float* in  = (const float*)d_in[0];
    const float* emb = (const float*)d_in[1];
    float* out = (float*)d_out;
    char* ws = (char*)d_ws;
    int*    idx    = (int*)(ws + WS_IDX);
    float*  Arow   = (float*)(ws + WS_A);
    float*  e2     = (float*)(ws + WS_E2);
    int*    counts = (int*)(ws + WS_COUNTS);
    double* ssep   = (double*)(ws + WS_SSE);

    k_zero<<<dim3(4), dim3(256), 0, stream>>>(counts);
    k_e2<<<dim3(4), dim3(256), 0, stream>>>(emb, e2);
    k_rowsum<<<dim3(256), dim3(256), 0, stream>>>(in, Arow);
    k_argmin<<<dim3(512), dim3(256), 0, stream>>>(in, emb, Arow, e2, idx, counts);
    k_quant<<<dim3(1024), dim3(256), 0, stream>>>(in, emb, idx, out + Q_OFF, ssep);
    k_enc<<<dim3(131072), dim3(256), 0, stream>>>(idx, out + ENC_OFF);
    k_final<<<dim3(1), dim3(256), 0, stream>>>(ssep, counts, out);
}

// Round 2
// 463.677 us; speedup vs baseline: 1.8213x; 1.8213x over previous
//
#include <hip/hip_runtime.h>
#include <cmath>
#include <cfloat>

#define NUM_EMB 1024
#define EMB_DIM 256
#define BATCH 32
#define SEQ 2048
#define NROWS 65536            // BATCH*SEQ
// d_out offsets (floats): [loss | quantized (b,c,l) | perplexity | encodings (N,K)]
#define Q_OFF 1
#define PERP_OFF 16777217
#define ENC_OFF 16777218
// ws offsets (bytes)
#define WS_IDX 0
#define WS_A      (NROWS * 4)
#define WS_E2     (WS_A + NROWS * 4)
#define WS_COUNTS (WS_E2 + NUM_EMB * 4)
#define WS_SSE    (WS_COUNTS + NUM_EMB * 4)
#define WS_EMX    (WS_SSE + 1024 * 8)

typedef __attribute__((ext_vector_type(8))) short short8v;
typedef __attribute__((ext_vector_type(16))) float f32x16;
#define MFMA(a,b,c) __builtin_amdgcn_mfma_f32_32x32x16_bf16(a,b,c,0,0,0)

// square with a barrier so the compiler cannot contract x*x into a following add
__device__ __forceinline__ float sqg(float x) {
    float s = x * x;
    asm volatile("" : "+v"(s));
    return s;
}

// RNE float->bf16 (no NaN inputs here)
__device__ __forceinline__ unsigned short f2bf(float f) {
    unsigned u = __float_as_uint(f);
    unsigned r = u + 0x7FFFu + ((u >> 16) & 1u);
    return (unsigned short)(r >> 16);
}

// order-preserving float<->uint maps (for LDS atomicMin on floats incl. negatives)
__device__ __forceinline__ unsigned f2ord(float f) {
    unsigned u = __float_as_uint(f);
    return (u & 0x80000000u) ? ~u : (u | 0x80000000u);
}
__device__ __forceinline__ float ord2f(unsigned o) {
    unsigned u = (o & 0x80000000u) ? (o & 0x7FFFFFFFu) : ~o;
    return __uint_as_float(u);
}

// numpy pairwise sum of squares over 256 elements (AVX512 path replica)
template <int STRIDE>
__device__ float np_sumsq256(const float* __restrict__ p) {
    float total = 0.0f;
#pragma unroll
    for (int h = 0; h < 2; ++h) {
        const int base = 128 * h;
        float c[16];
#pragma unroll
        for (int l = 0; l < 16; ++l) {
            float t0 = sqg(p[(size_t)(base + l) * STRIDE]);
            float t1 = sqg(p[(size_t)(base + 16 + l) * STRIDE]);
            float t2 = sqg(p[(size_t)(base + 32 + l) * STRIDE]);
            float t3 = sqg(p[(size_t)(base + 48 + l) * STRIDE]);
            float t4 = sqg(p[(size_t)(base + 64 + l) * STRIDE]);
            float t5 = sqg(p[(size_t)(base + 80 + l) * STRIDE]);
            float t6 = sqg(p[(size_t)(base + 96 + l) * STRIDE]);
            float t7 = sqg(p[(size_t)(base + 112 + l) * STRIDE]);
            c[l] = ((t0 + t1) + (t2 + t3)) + ((t4 + t5) + (t6 + t7));
        }
        float u[8];
#pragma unroll
        for (int l = 0; l < 8; ++l) u[l] = c[l] + c[l + 8];
        float v[4];
#pragma unroll
        for (int l = 0; l < 4; ++l) v[l] = u[l] + u[l + 4];
        float w0 = v[0] + v[2];
        float w1 = v[1] + v[3];
        float half = w0 + w1;
        total = (h == 0) ? half : (total + half);
    }
    return total;
}

__global__ void k_zero(int* __restrict__ counts, unsigned* __restrict__ emx) {
    int i = blockIdx.x * blockDim.x + threadIdx.x;
    if (i < NUM_EMB) counts[i] = 0;
    if (i == NUM_EMB) *emx = 0u;
}

__global__ __launch_bounds__(256) void k_e2(const float* __restrict__ emb,
                                            float* __restrict__ e2,
                                            unsigned* __restrict__ emx) {
    int k = blockIdx.x * 256 + threadIdx.x;
    float v = np_sumsq256<1>(emb + (size_t)k * EMB_DIM);
    e2[k] = v;
    __shared__ float red[256];
    red[threadIdx.x] = sqrtf(v);
    __syncthreads();
    for (int s = 128; s > 0; s >>= 1) {
        if (threadIdx.x < s) red[threadIdx.x] = fmaxf(red[threadIdx.x], red[threadIdx.x + s]);
        __syncthreads();
    }
    if (threadIdx.x == 0) atomicMax(emx, __float_as_uint(red[0]));
}

__global__ void k_rowsum(const float* __restrict__ in, float* __restrict__ Arow) {
    int n = blockIdx.x * blockDim.x + threadIdx.x;
    int b = n >> 11, l = n & 2047;
    Arow[n] = np_sumsq256<SEQ>(in + (size_t)b * (EMB_DIM * SEQ) + l);
}

// pre-convert E to bf16, PRE-SWIZZLED so k_dist staging is a linear copy that
// lands in the swizzled LDS image. prep[chunk][code][slot] (16B units):
// slot s of (chunk,code c) holds e[c][chunk*64 + 8*(s ^ (c&7)) + 0..7]
__global__ __launch_bounds__(256) void k_prep_e(const float* __restrict__ emb,
                                                char* __restrict__ ebf) {
    int t = blockIdx.x * 256 + threadIdx.x;   // 8192 threads
    int c = t >> 3;
    int s = t & 7;
#pragma unroll
    for (int ch = 0; ch < 4; ++ch) {
        int d0 = ch * 64 + 8 * (s ^ (c & 7));
        const float* e = emb + (size_t)c * EMB_DIM + d0;
        unsigned h[8];
#pragma unroll
        for (int j = 0; j < 8; ++j) h[j] = f2bf(e[j]);
        uint4 w;
        w.x = h[0] | (h[1] << 16);
        w.y = h[2] | (h[3] << 16);
        w.z = h[4] | (h[5] << 16);
        w.w = h[6] | (h[7] << 16);
        *(uint4*)(ebf + (size_t)ch * 131072 + (size_t)c * 128 + s * 16) = w;
    }
}

// MFMA approx-distance + per-row min + candidate collection.
// 512 blocks x 512 thr (8 waves, 2x4). Block: 128 rows x 1024 codes (2 tiles of 512).
// Wave tile 64x128 via 2x4 frags of 32x32x16 bf16.
__global__ __launch_bounds__(512, 2) void k_dist(
    const float* __restrict__ in, const char* __restrict__ ebf,
    const float* __restrict__ Arow, const float* __restrict__ e2g,
    const unsigned* __restrict__ emxp,
    int* __restrict__ cntg, int* __restrict__ listg)
{
    __shared__ __align__(16) char XsB[65536];   // [128 rows][256 d] bf16, swizzled
    __shared__ __align__(16) char EsB[65536];   // [512 codes][64 d] bf16, swizzled
    __shared__ unsigned rowMinU[128];
    __shared__ int rowCnt[128];
    __shared__ float wRow[128];
    __shared__ int rowList[128 * 16];

    const int tid = threadIdx.x;
    const int n0 = blockIdx.x << 7;
    const int b = n0 >> 11;
    const int l0 = n0 & 2047;
    const int lane = tid & 63;
    const int wv = tid >> 6;
    const int wrow = wv >> 2;   // 0..1
    const int wcol = wv & 3;    // 0..3
    const int lm = lane & 31;
    const int lh = lane >> 5;

    const float EMX = __uint_as_float(*emxp);

    for (int i = tid; i < 128; i += 512) {
        rowMinU[i] = 0xFFFFFFFFu;
        rowCnt[i] = 0;
        wRow[i] = 0.0078125f * sqrtf(Arow[n0 + i]) * EMX + 1.0e-4f;
    }

    // stage X tile -> bf16 swizzled LDS (coalesced global reads)
    for (int it = 0; it < 64; ++it) {
        int flat = it * 512 + tid;
        int d = flat >> 7;
        int r = flat & 127;
        float v = in[(size_t)b * 524288 + (size_t)d * 2048 + (l0 + r)];
        int off = r * 512 + ((2 * d) ^ ((r & 7) << 4));
        *(unsigned short*)(XsB + off) = f2bf(v);
    }

    int rbase[2], rsw[2], cbase[4], csw[4];
#pragma unroll
    for (int rf = 0; rf < 2; ++rf) {
        int r = wrow * 64 + rf * 32 + lm;
        rbase[rf] = r * 512;
        rsw[rf] = (r & 7) << 4;
    }
#pragma unroll
    for (int cf = 0; cf < 4; ++cf) {
        int c = wcol * 128 + cf * 32 + lm;   // within 512-code tile
        cbase[cf] = c * 128;
        csw[cf] = (c & 7) << 4;
    }

    for (int tile = 0; tile < 2; ++tile) {
        f32x16 acc[2][4];
#pragma unroll
        for (int rf = 0; rf < 2; ++rf)
#pragma unroll
            for (int cf = 0; cf < 4; ++cf)
#pragma unroll
                for (int i = 0; i < 16; ++i) acc[rf][cf][i] = 0.0f;

        for (int ch = 0; ch < 4; ++ch) {
            __syncthreads();
            {   // stage E chunk (linear copy of pre-swizzled image)
                const char* src = ebf + (size_t)ch * 131072 + (size_t)tile * 65536;
#pragma unroll
                for (int it = 0; it < 8; ++it) {
                    int o = it * 8192 + tid * 16;
                    *(uint4*)(EsB + o) = *(const uint4*)(src + o);
                }
            }
            __syncthreads();
            const int kbase = 128 * ch;
#pragma unroll
            for (int ks = 0; ks < 4; ++ks) {
                const int kk = 32 * ks + 16 * lh;
                short8v a0 = *(const short8v*)(XsB + rbase[0] + ((kbase + kk) ^ rsw[0]));
                short8v a1 = *(const short8v*)(XsB + rbase[1] + ((kbase + kk) ^ rsw[1]));
                short8v b0 = *(const short8v*)(EsB + cbase[0] + (kk ^ csw[0]));
                short8v b1 = *(const short8v*)(EsB + cbase[1] + (kk ^ csw[1]));
                short8v b2 = *(const short8v*)(EsB + cbase[2] + (kk ^ csw[2]));
                short8v b3 = *(const short8v*)(EsB + cbase[3] + (kk ^ csw[3]));
                acc[0][0] = MFMA(a0, b0, acc[0][0]);
                acc[0][1] = MFMA(a0, b1, acc[0][1]);
                acc[0][2] = MFMA(a0, b2, acc[0][2]);
                acc[0][3] = MFMA(a0, b3, acc[0][3]);
                acc[1][0] = MFMA(a1, b0, acc[1][0]);
                acc[1][1] = MFMA(a1, b1, acc[1][1]);
                acc[1][2] = MFMA(a1, b2, acc[1][2]);
                acc[1][3] = MFMA(a1, b3, acc[1][3]);
            }
        }

        // epilogue: s~ = e2 - 2*dot~ ; per-row running min, then collect candidates
        float e2v[4];
#pragma unroll
        for (int cf = 0; cf < 4; ++cf)
            e2v[cf] = e2g[tile * 512 + wcol * 128 + cf * 32 + lm];

#pragma unroll
        for (int rf = 0; rf < 2; ++rf) {
#pragma unroll
            for (int i = 0; i < 16; ++i) {
                float m = e2v[0] - 2.0f * acc[rf][0][i];
                m = fminf(m, e2v[1] - 2.0f * acc[rf][1][i]);
                m = fminf(m, e2v[2] - 2.0f * acc[rf][2][i]);
                m = fminf(m, e2v[3] - 2.0f * acc[rf][3][i]);
#pragma unroll
                for (int mk = 1; mk < 32; mk <<= 1)
                    m = fminf(m, __shfl_xor(m, mk));
                if (lm == 0) {
                    int rr = wrow * 64 + rf * 32 + (i & 3) + 8 * (i >> 2) + 4 * lh;
                    atomicMin(&rowMinU[rr], f2ord(m));
                }
            }
        }
        __syncthreads();
#pragma unroll
        for (int rf = 0; rf < 2; ++rf) {
#pragma unroll
            for (int cf = 0; cf < 4; ++cf) {
#pragma unroll
                for (int i = 0; i < 16; ++i) {
                    int rr = wrow * 64 + rf * 32 + (i & 3) + 8 * (i >> 2) + 4 * lh;
                    float sv = e2v[cf] - 2.0f * acc[rf][cf][i];
                    float thr = ord2f(rowMinU[rr]) + wRow[rr];
                    if (sv <= thr) {
                        int p = atomicAdd(&rowCnt[rr], 1);
                        if (p < 16) rowList[rr * 16 + p] = tile * 512 + wcol * 128 + cf * 32 + lm;
                    }
                }
            }
        }
        __syncthreads();
    }

    if (tid < 128) cntg[n0 + tid] = rowCnt[tid];
    for (int f = tid; f < 2048; f += 512)
        listg[(size_t)n0 * 16 + f] = rowList[f];
}

// exact rescore of candidates: bit-exact numpy pipeline (validated in R1)
__global__ __launch_bounds__(128) void k_rescore(
    const float* __restrict__ in, const float* __restrict__ emb,
    const float* __restrict__ Arow, const float* __restrict__ e2,
    const int* __restrict__ cntg, const int* __restrict__ listg,
    int* __restrict__ idx, int* __restrict__ counts)
{
    const int n = blockIdx.x * 128 + threadIdx.x;
    const int b = n >> 11, l = n & 2047;
    const float* xb = in + (size_t)b * 524288 + l;   // x_d at xb[d*2048]
    const int cnt = cntg[n];
    const bool ovf = cnt > 16;
    const int ce = ovf ? NUM_EMB : cnt;
    const float A = Arow[n];
    float bestd = FLT_MAX;
    int bestk = 0x7FFFFFFF;
    for (int s = 0;; ++s) {
        bool act = s < ce;
        if (!__any(act)) break;
        if (act) {
            int k = ovf ? s : listg[(size_t)n * 16 + s];
            const float* er = emb + (size_t)k * EMB_DIM;
            float acc = 0.0f;
            for (int d = 0; d < 256; ++d)
                acc = __builtin_fmaf(xb[(size_t)d * 2048], er[d], acc);
            float t = A + e2[k];
            float dist = t - 2.0f * acc;
            if (dist < bestd || (dist == bestd && k < bestk)) { bestd = dist; bestk = k; }
        }
    }
    idx[n] = bestk;
    atomicAdd(&counts[bestk], 1);
}

// quantized output: out[b,c,l] = emb[idx[n], c] via LDS transpose; fused SSE partials
__global__ __launch_bounds__(256) void k_quant(
    const float* __restrict__ in, const float* __restrict__ emb,
    const int* __restrict__ idx, float* __restrict__ qout, double* __restrict__ ssep)
{
    __shared__ float T[256][65];
    __shared__ int lidx[64];
    __shared__ double rd[256];
    const int tid = threadIdx.x;
    const int bid = blockIdx.x;
    const int b = bid >> 5;
    const int l0 = (bid & 31) << 6;
    const int nb = b * SEQ + l0;
    if (tid < 64) lidx[tid] = idx[nb + tid];
    __syncthreads();
#pragma unroll 4
    for (int l = 0; l < 64; ++l) {
        T[tid][l] = emb[(size_t)lidx[l] * EMB_DIM + tid];
    }
    __syncthreads();
    double sse = 0.0;
    const int lo = tid & 63;
    const int ch = tid >> 6;
    for (int it = 0; it < 64; ++it) {
        const int c = (it << 2) + ch;
        const size_t g = (size_t)b * (EMB_DIM * SEQ) + (size_t)c * SEQ + l0 + lo;
        const float q = T[c][lo];
        const float x = in[g];
        qout[g] = q;
        const float d = q - x;
        sse += (double)d * (double)d;
    }
    rd[tid] = sse;
    __syncthreads();
    for (int s = 128; s > 0; s >>= 1) {
        if (tid < s) rd[tid] += rd[tid + s];
        __syncthreads();
    }
    if (tid == 0) ssep[bid] = rd[0];
}

__global__ __launch_bounds__(256) void k_enc(const int* __restrict__ idx, float* __restrict__ enc) {
    const int gid = blockIdx.x * 256 + threadIdx.x;
    const int n = gid >> 9;
    const int kk = (gid & 511) << 1;
    const int e = idx[n];
    float2 v;
    v.x = (e == kk) ? 1.0f : 0.0f;
    v.y = (e == kk + 1) ? 1.0f : 0.0f;
    *(float2*)(enc + (size_t)n * NUM_EMB + kk) = v;
}

__global__ __launch_bounds__(256) void k_final(const double* __restrict__ ssep,
                                               const int* __restrict__ counts,
                                               float* __restrict__ out)
{
    __shared__ double rd[256];
    const int tid = threadIdx.x;
    double s = 0.0;
    for (int i = tid; i < 1024; i += 256) s += ssep[i];
    rd[tid] = s;
    __syncthreads();
    for (int st = 128; st > 0; st >>= 1) {
        if (tid < st) rd[tid] += rd[tid + st];
        __syncthreads();
    }
    const double total = rd[0];
    __syncthreads();
    double pl = 0.0;
    for (int k = tid; k < 1024; k += 256) {
        const double p = (double)counts[k] * (1.0 / 65536.0);
        pl += p * log(p + 1e-10);
    }
    rd[tid] = pl;
    __syncthreads();
    for (int st = 128; st > 0; st >>= 1) {
        if (tid < st) rd[tid] += rd[tid + st];
        __syncthreads();
    }
    if (tid == 0) {
        out[0] = (float)(1.25 * (total * (1.0 / 16777216.0)));
        out[PERP_OFF] = (float)exp(-rd[0]);
    }
}

extern "C" void kernel_launch(void* const* d_in, const int* in_sizes, int n_in,
                              void* d_out, int out_size, void* d_ws, size_t ws_size,
                              hipStream_t stream)
{
    const float* in  = (const float*)d_in[0];
    const float* emb = (const float*)d_in[1];
    float* out = (float*)d_out;
    char* ws = (char*)d_ws;
    int*      idx    = (int*)(ws + WS_IDX);
    float*    Arow   = (float*)(ws + WS_A);
    float*    e2     = (float*)(ws + WS_E2);
    int*      counts = (int*)(ws + WS_COUNTS);
    double*   ssep   = (double*)(ws + WS_SSE);
    unsigned* emx    = (unsigned*)(ws + WS_EMX);

    // scratch carved from output regions (overwritten later by k_quant / k_enc)
    char* ebf  = (char*)d_out + ((size_t)ENC_OFF * 4 + 8);   // 16B-aligned, 512 KB
    int* cntg  = (int*)((char*)d_out + (size_t)Q_OFF * 4);   // 256 KB
    int* listg = cntg + NROWS;                               // 4 MB

    k_zero<<<dim3(5), dim3(256), 0, stream>>>(counts, emx);
    k_e2<<<dim3(4), dim3(256), 0, stream>>>(emb, e2, emx);
    k_rowsum<<<dim3(256), dim3(256), 0, stream>>>(in, Arow);
    k_prep_e<<<dim3(32), dim3(256), 0, stream>>>(emb, ebf);
    k_dist<<<dim3(512), dim3(512), 0, stream>>>(in, ebf, Arow, e2, emx, cntg, listg);
    k_rescore<<<dim3(512), dim3(128), 0, stream>>>(in, emb, Arow, e2, cntg, listg, idx, counts);
    k_quant<<<dim3(1024), dim3(256), 0, stream>>>(in, emb, idx, out + Q_OFF, ssep);
    k_enc<<<dim3(131072), dim3(256), 0, stream>>>(idx, out + ENC_OFF);
    k_final<<<dim3(1), dim3(256), 0, stream>>>(ssep, counts, out);
}

// Round 3
// 427.047 us; speedup vs baseline: 1.9776x; 1.0858x over previous
//
#include <hip/hip_runtime.h>
#include <cmath>
#include <cfloat>

#define NUM_EMB 1024
#define EMB_DIM 256
#define BATCH 32
#define SEQ 2048
#define NROWS 65536            // BATCH*SEQ
// d_out offsets (floats): [loss | quantized (b,c,l) | perplexity | encodings (N,K)]
#define Q_OFF 1
#define PERP_OFF 16777217
#define ENC_OFF 16777218
// ws offsets (bytes)
#define WS_IDX 0
#define WS_E2     (NROWS * 4)
#define WS_COUNTS (WS_E2 + NUM_EMB * 4)
#define WS_SSE    (WS_COUNTS + NUM_EMB * 4)
#define WS_EMX    (WS_SSE + 1024 * 8)

typedef __attribute__((ext_vector_type(8))) short short8v;
typedef __attribute__((ext_vector_type(16))) float f32x16;
#define MFMA(a,b,c) __builtin_amdgcn_mfma_f32_32x32x16_bf16(a,b,c,0,0,0)

// square with a barrier so the compiler cannot contract x*x into a following add
__device__ __forceinline__ float sqg(float x) {
    float s = x * x;
    asm volatile("" : "+v"(s));
    return s;
}

// RNE float->bf16
__device__ __forceinline__ unsigned short f2bf(float f) {
    unsigned u = __float_as_uint(f);
    unsigned r = u + 0x7FFFu + ((u >> 16) & 1u);
    return (unsigned short)(r >> 16);
}

// order-preserving float<->uint maps (LDS atomicMin on floats)
__device__ __forceinline__ unsigned f2ord(float f) {
    unsigned u = __float_as_uint(f);
    return (u & 0x80000000u) ? ~u : (u | 0x80000000u);
}
__device__ __forceinline__ float ord2f(unsigned o) {
    unsigned u = (o & 0x80000000u) ? (o & 0x7FFFFFFFu) : ~o;
    return __uint_as_float(u);
}

// numpy pairwise sum of squares over 256 elements (AVX512 path replica)
template <int STRIDE>
__device__ float np_sumsq256(const float* __restrict__ p) {
    float total = 0.0f;
#pragma unroll
    for (int h = 0; h < 2; ++h) {
        const int base = 128 * h;
        float c[16];
#pragma unroll
        for (int l = 0; l < 16; ++l) {
            float t0 = sqg(p[(size_t)(base + l) * STRIDE]);
            float t1 = sqg(p[(size_t)(base + 16 + l) * STRIDE]);
            float t2 = sqg(p[(size_t)(base + 32 + l) * STRIDE]);
            float t3 = sqg(p[(size_t)(base + 48 + l) * STRIDE]);
            float t4 = sqg(p[(size_t)(base + 64 + l) * STRIDE]);
            float t5 = sqg(p[(size_t)(base + 80 + l) * STRIDE]);
            float t6 = sqg(p[(size_t)(base + 96 + l) * STRIDE]);
            float t7 = sqg(p[(size_t)(base + 112 + l) * STRIDE]);
            c[l] = ((t0 + t1) + (t2 + t3)) + ((t4 + t5) + (t6 + t7));
        }
        float u[8];
#pragma unroll
        for (int l = 0; l < 8; ++l) u[l] = c[l] + c[l + 8];
        float v[4];
#pragma unroll
        for (int l = 0; l < 4; ++l) v[l] = u[l] + u[l + 4];
        float w0 = v[0] + v[2];
        float w1 = v[1] + v[3];
        float hh = w0 + w1;
        total = (h == 0) ? hh : (total + hh);
    }
    return total;
}

__global__ void k_zero(int* __restrict__ counts, unsigned* __restrict__ emx) {
    int i = blockIdx.x * blockDim.x + threadIdx.x;
    if (i < NUM_EMB) counts[i] = 0;
    if (i == NUM_EMB) *emx = 0u;
}

__global__ __launch_bounds__(256) void k_e2(const float* __restrict__ emb,
                                            float* __restrict__ e2,
                                            unsigned* __restrict__ emx) {
    int k = blockIdx.x * 256 + threadIdx.x;
    float v = np_sumsq256<1>(emb + (size_t)k * EMB_DIM);
    e2[k] = v;
    __shared__ float red[256];
    red[threadIdx.x] = sqrtf(v);
    __syncthreads();
    for (int s = 128; s > 0; s >>= 1) {
        if (threadIdx.x < s) red[threadIdx.x] = fmaxf(red[threadIdx.x], red[threadIdx.x + s]);
        __syncthreads();
    }
    if (threadIdx.x == 0) atomicMax(emx, __float_as_uint(red[0]));
}

// bf16 E image laid out for DIRECT coalesced B-fragment loads:
// ebf[p][c] = 16 bytes = e[c][8p .. 8p+7] in bf16   (p = 0..31, c = 0..1023)
__global__ __launch_bounds__(256) void k_prep_e(const float* __restrict__ emb,
                                                char* __restrict__ ebf) {
    int t = blockIdx.x * 256 + threadIdx.x;   // 8192 threads
    int c = t & 1023;
    int s = t >> 10;                          // 0..7
#pragma unroll
    for (int g = 0; g < 4; ++g) {
        int p = s + 8 * g;
        const float* e = emb + (size_t)c * EMB_DIM + 8 * p;
        unsigned h[8];
#pragma unroll
        for (int j = 0; j < 8; ++j) h[j] = f2bf(e[j]);
        uint4 w;
        w.x = h[0] | (h[1] << 16);
        w.y = h[2] | (h[3] << 16);
        w.z = h[4] | (h[5] << 16);
        w.w = h[6] | (h[7] << 16);
        *(uint4*)(ebf + ((size_t)p << 14) + ((size_t)c << 4)) = w;
    }
}

// Fused: X staging (+ exact numpy rowsum) -> barrier-free MFMA distance pass
// -> per-row min + candidate collect -> exact in-block rescore -> idx/counts.
// 512 blocks x 512 thr (8 waves = 2 row-waves x 4 col-waves). 128 rows x 1024 codes.
__global__ __launch_bounds__(512, 2) void k_dist(
    const float* __restrict__ in, const char* __restrict__ ebf,
    const float* __restrict__ emb, const float* __restrict__ e2g,
    const unsigned* __restrict__ emxp,
    int* __restrict__ idx, int* __restrict__ counts)
{
    __shared__ __align__(16) char XsB[65536];   // [128 rows][256 d] bf16, swizzled
    __shared__ float vpart[128][8];             // [row][h*4+o] exact pairwise partials
    __shared__ float A_lds[128];
    __shared__ float wRow[128];
    __shared__ unsigned rowMinU[128];
    __shared__ int rowCnt[128];
    __shared__ int rowList[128 * 16];

    const int tid = threadIdx.x;
    const int n0 = blockIdx.x << 7;
    const int b = n0 >> 11;
    const int l0 = n0 & 2047;
    const int lane = tid & 63;
    const int wv = tid >> 6;
    const int wrow = wv >> 2;   // 0..1
    const int wcol = wv & 3;    // 0..3
    const int lm = lane & 31;
    const int lh = lane >> 5;

    if (tid < 128) { rowMinU[tid] = 0xFFFFFFFFu; rowCnt[tid] = 0; }

    // ---- stage X (bf16, swizzled) + exact numpy-pairwise row sum-of-squares ----
    {
        const int o = tid >> 7;          // d residue class (mod 4)
        const int r = tid & 127;         // row
        const float* xcol = in + (size_t)b * 524288 + l0 + r;
#pragma unroll
        for (int h = 0; h < 2; ++h) {
            float tarr[32];              // tarr[4m+j] = square of x[128h + (o+4j) + 16m]
#pragma unroll
            for (int it = 0; it < 32; ++it) {
                const int d = 128 * h + 4 * it + o;
                float v = xcol[(size_t)d * 2048];
                *(unsigned short*)(XsB + r * 512 + ((2 * d) ^ ((r & 7) << 4))) = f2bf(v);
                tarr[it] = sqg(v);
            }
            float cj[4];
#pragma unroll
            for (int j = 0; j < 4; ++j)
                cj[j] = ((tarr[j] + tarr[4 + j]) + (tarr[8 + j] + tarr[12 + j]))
                      + ((tarr[16 + j] + tarr[20 + j]) + (tarr[24 + j] + tarr[28 + j]));
            // v[o] = u[o] + u[o+4] = (c[o]+c[o+8]) + (c[o+4]+c[o+12])
            vpart[r][h * 4 + o] = (cj[0] + cj[2]) + (cj[1] + cj[3]);
        }
    }
    __syncthreads();
    const float EMX = __uint_as_float(*emxp);
    if (tid < 128) {
        const float* vp = vpart[tid];
        float h0 = (vp[0] + vp[2]) + (vp[1] + vp[3]);   // (v0+v2)+(v1+v3)
        float h1 = (vp[4] + vp[6]) + (vp[5] + vp[7]);
        float A = h0 + h1;
        A_lds[tid] = A;
        wRow[tid] = 0.015625f * sqrtf(A) * EMX + 2.0e-4f;   // 2*2^-7 * ||x|| * max||e|| + slop
    }
    __syncthreads();

    // per-wave A-fragment bases
    int rbase[2], rsw[2];
#pragma unroll
    for (int rf = 0; rf < 2; ++rf) {
        int r = wrow * 64 + rf * 32 + lm;
        rbase[rf] = r * 512;
        rsw[rf] = (r & 7) << 4;
    }

    for (int tile = 0; tile < 2; ++tile) {
        int cidx[4];
#pragma unroll
        for (int cf = 0; cf < 4; ++cf)
            cidx[cf] = tile * 512 + wcol * 128 + cf * 32 + lm;

        f32x16 acc[2][4];
#pragma unroll
        for (int rf = 0; rf < 2; ++rf)
#pragma unroll
            for (int cf = 0; cf < 4; ++cf)
#pragma unroll
                for (int i = 0; i < 16; ++i) acc[rf][cf][i] = 0.0f;

        // barrier-free main loop: A from LDS, B direct from L2-resident image
        for (int ch = 0; ch < 4; ++ch) {
#pragma unroll
            for (int ks = 0; ks < 4; ++ks) {
                const int koff = 128 * ch + 32 * ks + 16 * lh;   // byte offset in X row
                const int p = 8 * ch + 2 * ks + lh;              // d8-block
                const char* bp = ebf + ((size_t)p << 14);
                short8v b0 = *(const short8v*)(bp + ((size_t)cidx[0] << 4));
                short8v b1 = *(const short8v*)(bp + ((size_t)cidx[1] << 4));
                short8v b2 = *(const short8v*)(bp + ((size_t)cidx[2] << 4));
                short8v b3 = *(const short8v*)(bp + ((size_t)cidx[3] << 4));
                short8v a0 = *(const short8v*)(XsB + rbase[0] + (koff ^ rsw[0]));
                short8v a1 = *(const short8v*)(XsB + rbase[1] + (koff ^ rsw[1]));
                acc[0][0] = MFMA(a0, b0, acc[0][0]);
                acc[0][1] = MFMA(a0, b1, acc[0][1]);
                acc[0][2] = MFMA(a0, b2, acc[0][2]);
                acc[0][3] = MFMA(a0, b3, acc[0][3]);
                acc[1][0] = MFMA(a1, b0, acc[1][0]);
                acc[1][1] = MFMA(a1, b1, acc[1][1]);
                acc[1][2] = MFMA(a1, b2, acc[1][2]);
                acc[1][3] = MFMA(a1, b3, acc[1][3]);
            }
        }

        // epilogue: s~ = e2 - 2*dot~ ; per-row running min, then candidate collect
        float e2v[4];
#pragma unroll
        for (int cf = 0; cf < 4; ++cf) e2v[cf] = e2g[cidx[cf]];

#pragma unroll
        for (int rf = 0; rf < 2; ++rf) {
#pragma unroll
            for (int i = 0; i < 16; ++i) {
                float m = e2v[0] - 2.0f * acc[rf][0][i];
                m = fminf(m, e2v[1] - 2.0f * acc[rf][1][i]);
                m = fminf(m, e2v[2] - 2.0f * acc[rf][2][i]);
                m = fminf(m, e2v[3] - 2.0f * acc[rf][3][i]);
#pragma unroll
                for (int mk = 1; mk < 32; mk <<= 1)
                    m = fminf(m, __shfl_xor(m, mk));
                if (lm == 0) {
                    int rr = wrow * 64 + rf * 32 + (i & 3) + 8 * (i >> 2) + 4 * lh;
                    atomicMin(&rowMinU[rr], f2ord(m));
                }
            }
        }
        __syncthreads();
#pragma unroll
        for (int rf = 0; rf < 2; ++rf) {
#pragma unroll
            for (int cf = 0; cf < 4; ++cf) {
#pragma unroll
                for (int i = 0; i < 16; ++i) {
                    int rr = wrow * 64 + rf * 32 + (i & 3) + 8 * (i >> 2) + 4 * lh;
                    float sv = e2v[cf] - 2.0f * acc[rf][cf][i];
                    float thr = ord2f(rowMinU[rr]) + wRow[rr];
                    if (sv <= thr) {
                        int pslot = atomicAdd(&rowCnt[rr], 1);
                        if (pslot < 16) rowList[rr * 16 + pslot] = cidx[cf];
                    }
                }
            }
        }
        __syncthreads();
    }

    // ---- exact in-block rescore (bit-exact numpy/OpenBLAS pipeline) ----
    if (tid < 128) {
        const int rr = tid;
        const int cnt = rowCnt[rr];
        int bestk;
        if (cnt == 1) {
            bestk = rowList[rr * 16];
        } else {
            const bool ovf = cnt > 16;
            const int ce = ovf ? NUM_EMB : cnt;
            const float* xb = in + (size_t)b * 524288 + (l0 + rr);
            const float A = A_lds[rr];
            float bestd = FLT_MAX;
            bestk = 0x7FFFFFFF;
            for (int s = 0; s < ce; ++s) {
                const int k = ovf ? s : rowList[rr * 16 + s];
                const float* er = emb + (size_t)k * EMB_DIM;
                float acc2 = 0.0f;
                for (int d = 0; d < 256; ++d)
                    acc2 = __builtin_fmaf(xb[(size_t)d * 2048], er[d], acc2);
                const float t = A + e2g[k];
                const float dist = t - 2.0f * acc2;
                if (dist < bestd || (dist == bestd && k < bestk)) { bestd = dist; bestk = k; }
            }
        }
        idx[n0 + rr] = bestk;
        atomicAdd(&counts[bestk], 1);
    }
}

// quantized output: out[b,c,l] = emb[idx[n], c] via LDS transpose; fused SSE partials
__global__ __launch_bounds__(256) void k_quant(
    const float* __restrict__ in, const float* __restrict__ emb,
    const int* __restrict__ idx, float* __restrict__ qout, double* __restrict__ ssep)
{
    __shared__ float T[256][65];
    __shared__ int lidx[64];
    __shared__ double rd[256];
    const int tid = threadIdx.x;
    const int bid = blockIdx.x;
    const int b = bid >> 5;
    const int l0 = (bid & 31) << 6;
    const int nb = b * SEQ + l0;
    if (tid < 64) lidx[tid] = idx[nb + tid];
    __syncthreads();
#pragma unroll 4
    for (int l = 0; l < 64; ++l) {
        T[tid][l] = emb[(size_t)lidx[l] * EMB_DIM + tid];
    }
    __syncthreads();
    double sse = 0.0;
    const int lo = tid & 63;
    const int ch = tid >> 6;
    for (int it = 0; it < 64; ++it) {
        const int c = (it << 2) + ch;
        const size_t g = (size_t)b * (EMB_DIM * SEQ) + (size_t)c * SEQ + l0 + lo;
        const float q = T[c][lo];
        const float x = in[g];
        qout[g] = q;
        const float d = q - x;
        sse += (double)d * (double)d;
    }
    rd[tid] = sse;
    __syncthreads();
    for (int s = 128; s > 0; s >>= 1) {
        if (tid < s) rd[tid] += rd[tid + s];
        __syncthreads();
    }
    if (tid == 0) ssep[bid] = rd[0];
}

// one-hot encodings: float4 stores, every element rewritten every call
__global__ __launch_bounds__(256) void k_enc(const int* __restrict__ idx, float* __restrict__ enc) {
    const int gid = blockIdx.x * 256 + threadIdx.x;   // 16777216 threads
    const int n = gid >> 8;
    const int kk = (gid & 255) << 2;
    const int e = idx[n];
    float4 v;
    v.x = (e == kk) ? 1.0f : 0.0f;
    v.y = (e == kk + 1) ? 1.0f : 0.0f;
    v.z = (e == kk + 2) ? 1.0f : 0.0f;
    v.w = (e == kk + 3) ? 1.0f : 0.0f;
    *(float4*)(enc + (size_t)n * NUM_EMB + kk) = v;
}

__global__ __launch_bounds__(256) void k_final(const double* __restrict__ ssep,
                                               const int* __restrict__ counts,
                                               float* __restrict__ out)
{
    __shared__ double rd[256];
    const int tid = threadIdx.x;
    double s = 0.0;
    for (int i = tid; i < 1024; i += 256) s += ssep[i];
    rd[tid] = s;
    __syncthreads();
    for (int st = 128; st > 0; st >>= 1) {
        if (tid < st) rd[tid] += rd[tid + st];
        __syncthreads();
    }
    const double total = rd[0];
    __syncthreads();
    double pl = 0.0;
    for (int k = tid; k < 1024; k += 256) {
        const double p = (double)counts[k] * (1.0 / 65536.0);
        pl += p * log(p + 1e-10);
    }
    rd[tid] = pl;
    __syncthreads();
    for (int st = 128; st > 0; st >>= 1) {
        if (tid < st) rd[tid] += rd[tid + st];
        __syncthreads();
    }
    if (tid == 0) {
        out[0] = (float)(1.25 * (total * (1.0 / 16777216.0)));
        out[PERP_OFF] = (float)exp(-rd[0]);
    }
}

extern "C" void kernel_launch(void* const* d_in, const int* in_sizes, int n_in,
                              void* d_out, int out_size, void* d_ws, size_t ws_size,
                              hipStream_t stream)
{
    const float* in  = (const float*)d_in[0];
    const float* emb = (const float*)d_in[1];
    float* out = (float*)d_out;
    char* ws = (char*)d_ws;
    int*      idx    = (int*)(ws + WS_IDX);
    float*    e2     = (float*)(ws + WS_E2);
    int*      counts = (int*)(ws + WS_COUNTS);
    double*   ssep   = (double*)(ws + WS_SSE);
    unsigned* emx    = (unsigned*)(ws + WS_EMX);

    // bf16 E image carved from the encodings output region (overwritten later by k_enc)
    char* ebf = (char*)d_out + ((size_t)ENC_OFF * 4 + 8);   // 16B-aligned, 512 KB

    k_zero<<<dim3(5), dim3(256), 0, stream>>>(counts, emx);
    k_e2<<<dim3(4), dim3(256), 0, stream>>>(emb, e2, emx);
    k_prep_e<<<dim3(32), dim3(256), 0, stream>>>(emb, ebf);
    k_dist<<<dim3(512), dim3(512), 0, stream>>>(in, ebf, emb, e2, emx, idx, counts);
    k_quant<<<dim3(1024), dim3(256), 0, stream>>>(in, emb, idx, out + Q_OFF, ssep);
    k_enc<<<dim3(65536), dim3(256), 0, stream>>>(idx, out + ENC_OFF);
    k_final<<<dim3(1), dim3(256), 0, stream>>>(ssep, counts, out);
}

// Round 4
// 330.057 us; speedup vs baseline: 2.5587x; 1.2939x over previous
//
#include <hip/hip_runtime.h>
#include <cmath>
#include <cfloat>

#define NUM_EMB 1024
#define EMB_DIM 256
#define BATCH 32
#define SEQ 2048
#define NROWS 65536            // BATCH*SEQ
// d_out offsets (floats): [loss | quantized (b,c,l) | perplexity | encodings (N,K)]
#define Q_OFF 1
#define PERP_OFF 16777217
#define ENC_OFF 16777218
// ws offsets (bytes)
#define WS_IDX 0
#define WS_E2     (NROWS * 4)
#define WS_COUNTS (WS_E2 + NUM_EMB * 4)
#define WS_SSE    (WS_COUNTS + NUM_EMB * 4)
#define WS_EMX    (WS_SSE + 1024 * 8)

typedef __attribute__((ext_vector_type(8))) short short8v;
typedef __attribute__((ext_vector_type(16))) float f32x16;
#define MFMA(a,b,c) __builtin_amdgcn_mfma_f32_32x32x16_bf16(a,b,c,0,0,0)

// square with a barrier so the compiler cannot contract x*x into a following add
__device__ __forceinline__ float sqg(float x) {
    float s = x * x;
    asm volatile("" : "+v"(s));
    return s;
}

// RNE float->bf16
__device__ __forceinline__ unsigned short f2bf(float f) {
    unsigned u = __float_as_uint(f);
    unsigned r = u + 0x7FFFu + ((u >> 16) & 1u);
    return (unsigned short)(r >> 16);
}

// order-preserving float<->uint maps
__device__ __forceinline__ unsigned f2ord(float f) {
    unsigned u = __float_as_uint(f);
    return (u & 0x80000000u) ? ~u : (u | 0x80000000u);
}
__device__ __forceinline__ float ord2f(unsigned o) {
    unsigned u = (o & 0x80000000u) ? (o & 0x7FFFFFFFu) : ~o;
    return __uint_as_float(u);
}

// exact OpenBLAS-order dot: single accumulator, ascending d, fmaf
__device__ float exact_dot256(const float* __restrict__ xb, const float* __restrict__ er) {
    float acc = 0.0f;
    for (int d = 0; d < 256; d += 8) {
        float4 ea = *(const float4*)(er + d);
        float4 eb = *(const float4*)(er + d + 4);
        float x0 = xb[(size_t)(d + 0) * 2048];
        float x1 = xb[(size_t)(d + 1) * 2048];
        float x2 = xb[(size_t)(d + 2) * 2048];
        float x3 = xb[(size_t)(d + 3) * 2048];
        float x4 = xb[(size_t)(d + 4) * 2048];
        float x5 = xb[(size_t)(d + 5) * 2048];
        float x6 = xb[(size_t)(d + 6) * 2048];
        float x7 = xb[(size_t)(d + 7) * 2048];
        acc = __builtin_fmaf(x0, ea.x, acc);
        acc = __builtin_fmaf(x1, ea.y, acc);
        acc = __builtin_fmaf(x2, ea.z, acc);
        acc = __builtin_fmaf(x3, ea.w, acc);
        acc = __builtin_fmaf(x4, eb.x, acc);
        acc = __builtin_fmaf(x5, eb.y, acc);
        acc = __builtin_fmaf(x6, eb.z, acc);
        acc = __builtin_fmaf(x7, eb.w, acc);
    }
    return acc;
}

// numpy pairwise sum of squares over 256 elements (AVX512 path replica)
template <int STRIDE>
__device__ float np_sumsq256(const float* __restrict__ p) {
    float total = 0.0f;
#pragma unroll
    for (int h = 0; h < 2; ++h) {
        const int base = 128 * h;
        float c[16];
#pragma unroll
        for (int l = 0; l < 16; ++l) {
            float t0 = sqg(p[(size_t)(base + l) * STRIDE]);
            float t1 = sqg(p[(size_t)(base + 16 + l) * STRIDE]);
            float t2 = sqg(p[(size_t)(base + 32 + l) * STRIDE]);
            float t3 = sqg(p[(size_t)(base + 48 + l) * STRIDE]);
            float t4 = sqg(p[(size_t)(base + 64 + l) * STRIDE]);
            float t5 = sqg(p[(size_t)(base + 80 + l) * STRIDE]);
            float t6 = sqg(p[(size_t)(base + 96 + l) * STRIDE]);
            float t7 = sqg(p[(size_t)(base + 112 + l) * STRIDE]);
            c[l] = ((t0 + t1) + (t2 + t3)) + ((t4 + t5) + (t6 + t7));
        }
        float u[8];
#pragma unroll
        for (int l = 0; l < 8; ++l) u[l] = c[l] + c[l + 8];
        float v[4];
#pragma unroll
        for (int l = 0; l < 4; ++l) v[l] = u[l] + u[l + 4];
        float w0 = v[0] + v[2];
        float w1 = v[1] + v[3];
        float hh = w0 + w1;
        total = (h == 0) ? hh : (total + hh);
    }
    return total;
}

__global__ void k_zero(int* __restrict__ counts, unsigned* __restrict__ emx) {
    int i = blockIdx.x * blockDim.x + threadIdx.x;
    if (i < NUM_EMB) counts[i] = 0;
    if (i == NUM_EMB) *emx = 0u;
}

__global__ __launch_bounds__(256) void k_e2(const float* __restrict__ emb,
                                            float* __restrict__ e2,
                                            unsigned* __restrict__ emx) {
    int k = blockIdx.x * 256 + threadIdx.x;
    float v = np_sumsq256<1>(emb + (size_t)k * EMB_DIM);
    e2[k] = v;
    __shared__ float red[256];
    red[threadIdx.x] = sqrtf(v);
    __syncthreads();
    for (int s = 128; s > 0; s >>= 1) {
        if (threadIdx.x < s) red[threadIdx.x] = fmaxf(red[threadIdx.x], red[threadIdx.x + s]);
        __syncthreads();
    }
    if (threadIdx.x == 0) atomicMax(emx, __float_as_uint(red[0]));
}

// bf16 E image for DIRECT coalesced B-fragment loads:
// ebf[p][c] = 16 bytes = e[c][8p .. 8p+7] bf16   (p = 0..31, c = 0..1023)
__global__ __launch_bounds__(256) void k_prep_e(const float* __restrict__ emb,
                                                char* __restrict__ ebf) {
    int t = blockIdx.x * 256 + threadIdx.x;   // 8192 threads
    int c = t & 1023;
    int s = t >> 10;                          // 0..7
#pragma unroll
    for (int g = 0; g < 4; ++g) {
        int p = s + 8 * g;
        const float* e = emb + (size_t)c * EMB_DIM + 8 * p;
        unsigned h[8];
#pragma unroll
        for (int j = 0; j < 8; ++j) h[j] = f2bf(e[j]);
        uint4 w;
        w.x = h[0] | (h[1] << 16);
        w.y = h[2] | (h[3] << 16);
        w.z = h[4] | (h[5] << 16);
        w.w = h[6] | (h[7] << 16);
        *(uint4*)(ebf + ((size_t)p << 14) + ((size_t)c << 4)) = w;
    }
}

// Fused distance+argmin: 1024 blocks x 256 thr (4 waves). Block: 64 rows x 1024
// codes in 4 passes of 256. Wave tile 64x64 (2x2 frags of 32x32x16), acc=64 VGPR.
// B direct from L2-resident pre-swizzled image, software-pipelined 1 deep.
// Candidates stored WITH approx score; re-filtered vs final min; queue rescore.
__global__ __launch_bounds__(256, 3) void k_dist(
    const float* __restrict__ in, const char* __restrict__ ebf,
    const float* __restrict__ emb, const float* __restrict__ e2g,
    const unsigned* __restrict__ emxp,
    int* __restrict__ idx, int* __restrict__ counts)
{
    __shared__ __align__(16) char pool[32768];  // X tile during passes; queue after
    __shared__ float vpart[64][8];
    __shared__ float A_lds[64];
    __shared__ float wRow[64];
    __shared__ unsigned rowMinU[64];
    __shared__ int rowCnt[64];
    __shared__ int2 rowList[64 * 16];           // {code, __float_as_int(sv)}
    __shared__ int qn;

    const int tid = threadIdx.x;
    const int n0 = blockIdx.x << 6;
    const int b = n0 >> 11;
    const int l0 = n0 & 2047;
    const int lane = tid & 63;
    const int wv = tid >> 6;    // wave id = code-column group = staging d-residue
    const int lm = lane & 31;
    const int lh = lane >> 5;

    if (tid < 64) { rowMinU[tid] = 0xFFFFFFFFu; rowCnt[tid] = 0; }
    if (tid == 0) qn = 0;

    // ---- stage X (bf16, 16-slot XOR swizzle) + exact numpy-pairwise rowsum ----
    {
        const int o = wv;               // d residue (mod 4)
        const int r = lane;             // row 0..63
        const float* xcol = in + (size_t)b * 524288 + l0 + r;
#pragma unroll
        for (int h = 0; h < 2; ++h) {
            float tarr[32];
#pragma unroll
            for (int it = 0; it < 32; ++it) {
                const int d = 128 * h + 4 * it + o;
                float v = xcol[(size_t)d * 2048];
                *(unsigned short*)(pool + r * 512 + ((2 * d) ^ ((r & 15) << 4))) = f2bf(v);
                tarr[it] = sqg(v);
            }
            float cj[4];
#pragma unroll
            for (int j = 0; j < 4; ++j)
                cj[j] = ((tarr[j] + tarr[4 + j]) + (tarr[8 + j] + tarr[12 + j]))
                      + ((tarr[16 + j] + tarr[20 + j]) + (tarr[24 + j] + tarr[28 + j]));
            vpart[r][h * 4 + o] = (cj[0] + cj[2]) + (cj[1] + cj[3]);
        }
    }
    __syncthreads();
    const float EMX = __uint_as_float(*emxp);
    if (tid < 64) {
        const float* vp = vpart[tid];
        float h0 = (vp[0] + vp[2]) + (vp[1] + vp[3]);
        float h1 = (vp[4] + vp[6]) + (vp[5] + vp[7]);
        float A = h0 + h1;
        A_lds[tid] = A;
        wRow[tid] = 0.015625f * sqrtf(A) * EMX + 2.0e-4f;
    }
    __syncthreads();

    const int rsw = (lm & 15) << 4;     // same for rows lm and lm+32
    const int rb0 = lm * 512;
    const int rb1 = (32 + lm) * 512;

    for (int pass = 0; pass < 4; ++pass) {
        const int c0 = pass * 256 + wv * 64 + lm;
        const int c1 = c0 + 32;

        f32x16 acc00, acc01, acc10, acc11;
#pragma unroll
        for (int i = 0; i < 16; ++i) { acc00[i] = 0.f; acc01[i] = 0.f; acc10[i] = 0.f; acc11[i] = 0.f; }

        // software-pipelined: B(ks+1) issued before MFMAs of ks
        const char* bp0 = ebf + ((size_t)lh << 14);
        short8v bc0 = *(const short8v*)(bp0 + ((size_t)c0 << 4));
        short8v bc1 = *(const short8v*)(bp0 + ((size_t)c1 << 4));
        for (int ks = 0; ks < 16; ++ks) {
            short8v bn0, bn1;
            if (ks < 15) {
                const char* nb = ebf + ((size_t)(2 * ks + 2 + lh) << 14);
                bn0 = *(const short8v*)(nb + ((size_t)c0 << 4));
                bn1 = *(const short8v*)(nb + ((size_t)c1 << 4));
            }
            const int koff = 32 * ks + 16 * lh;
            short8v a0 = *(const short8v*)(pool + rb0 + (koff ^ rsw));
            short8v a1 = *(const short8v*)(pool + rb1 + (koff ^ rsw));
            acc00 = MFMA(a0, bc0, acc00);
            acc01 = MFMA(a0, bc1, acc01);
            acc10 = MFMA(a1, bc0, acc10);
            acc11 = MFMA(a1, bc1, acc11);
            if (ks < 15) { bc0 = bn0; bc1 = bn1; }
        }

        const float e20 = e2g[c0];
        const float e21 = e2g[c1];

        // per-row min (monotone across passes)
#pragma unroll
        for (int i = 0; i < 16; ++i) {
            float m0 = fminf(e20 - 2.0f * acc00[i], e21 - 2.0f * acc01[i]);
            float m1 = fminf(e20 - 2.0f * acc10[i], e21 - 2.0f * acc11[i]);
#pragma unroll
            for (int mk = 1; mk < 32; mk <<= 1) {
                m0 = fminf(m0, __shfl_xor(m0, mk));
                m1 = fminf(m1, __shfl_xor(m1, mk));
            }
            if (lm == 0) {
                int base = (i & 3) + 8 * (i >> 2) + 4 * lh;
                atomicMin(&rowMinU[base], f2ord(m0));
                atomicMin(&rowMinU[base + 32], f2ord(m1));
            }
        }
        __syncthreads();

        // collect candidates vs current min (superset of final set; filtered later)
#pragma unroll
        for (int i = 0; i < 16; ++i) {
            const int base = (i & 3) + 8 * (i >> 2) + 4 * lh;
            const float thr0 = ord2f(rowMinU[base]) + wRow[base];
            const float thr1 = ord2f(rowMinU[base + 32]) + wRow[base + 32];
            float s00 = e20 - 2.0f * acc00[i];
            float s01 = e21 - 2.0f * acc01[i];
            float s10 = e20 - 2.0f * acc10[i];
            float s11 = e21 - 2.0f * acc11[i];
            if (s00 <= thr0) { int p = atomicAdd(&rowCnt[base], 1);      if (p < 16) rowList[base * 16 + p]        = make_int2(c0, __float_as_int(s00)); }
            if (s01 <= thr0) { int p = atomicAdd(&rowCnt[base], 1);      if (p < 16) rowList[base * 16 + p]        = make_int2(c1, __float_as_int(s01)); }
            if (s10 <= thr1) { int p = atomicAdd(&rowCnt[base + 32], 1); if (p < 16) rowList[(base + 32) * 16 + p] = make_int2(c0, __float_as_int(s10)); }
            if (s11 <= thr1) { int p = atomicAdd(&rowCnt[base + 32], 1); if (p < 16) rowList[(base + 32) * 16 + p] = make_int2(c1, __float_as_int(s11)); }
        }
        __syncthreads();
    }

    // ---- X tile dead: carve queue + rowBest from pool ----
    int2* queue = (int2*)pool;                                         // 8 KB
    unsigned long long* rowBest = (unsigned long long*)(pool + 8192);  // 512 B

    int myBest = -1;
    int myCnt = 0, myNv = 0;
    if (tid < 64) {
        const int rr = tid;
        myCnt = rowCnt[rr];
        if (myCnt > 16) {
            // overflow (prob ~0): exact full scan
            const float* xb = in + (size_t)b * 524288 + (l0 + rr);
            const float A = A_lds[rr];
            float bestd = FLT_MAX;
            int bestk = 0x7FFFFFFF;
            for (int k = 0; k < NUM_EMB; ++k) {
                float acc2 = exact_dot256(xb, emb + (size_t)k * EMB_DIM);
                float t = A + e2g[k];
                float dist = t - 2.0f * acc2;
                if (dist < bestd || (dist == bestd && k < bestk)) { bestd = dist; bestk = k; }
            }
            myBest = bestk;
        } else {
            const float thr = ord2f(rowMinU[rr]) + wRow[rr];
            int lk = -1;
            for (int s = 0; s < myCnt; ++s) {
                int2 en = rowList[rr * 16 + s];
                if (__int_as_float(en.y) <= thr) { ++myNv; lk = en.x; }
            }
            if (myNv == 1) {
                myBest = lk;
            } else {
                rowBest[rr] = ~0ull;
                for (int s = 0; s < myCnt; ++s) {
                    int2 en = rowList[rr * 16 + s];
                    if (__int_as_float(en.y) <= thr) {
                        int p = atomicAdd(&qn, 1);
                        queue[p] = make_int2(rr, en.x);
                    }
                }
            }
        }
    }
    __syncthreads();

    // queue rescore: one candidate per lane, exact bits, packed argmin w/ min-k ties
    const int QN = qn;
    for (int e = tid; e < QN; e += 256) {
        int2 en = queue[e];
        const int rr = en.x;
        const int k = en.y;
        const float* xb = in + (size_t)b * 524288 + (l0 + rr);
        float acc2 = exact_dot256(xb, emb + (size_t)k * EMB_DIM);
        float t = A_lds[rr] + e2g[k];
        float dist = t - 2.0f * acc2;
        unsigned long long pk = ((unsigned long long)f2ord(dist) << 32) | (unsigned)k;
        atomicMin(&rowBest[rr], pk);
    }
    __syncthreads();

    if (tid < 64) {
        int bk = myBest;
        if (bk < 0) bk = (int)(rowBest[tid] & 0xFFFFFFFFull);
        idx[n0 + tid] = bk;
        atomicAdd(&counts[bk], 1);
    }
}

// quantized output: out[b,c,l] = emb[idx[n], c] via LDS transpose; fused SSE partials
__global__ __launch_bounds__(256) void k_quant(
    const float* __restrict__ in, const float* __restrict__ emb,
    const int* __restrict__ idx, float* __restrict__ qout, double* __restrict__ ssep)
{
    __shared__ float T[256][65];
    __shared__ int lidx[64];
    __shared__ double rd[256];
    const int tid = threadIdx.x;
    const int bid = blockIdx.x;
    const int b = bid >> 5;
    const int l0 = (bid & 31) << 6;
    const int nb = b * SEQ + l0;
    if (tid < 64) lidx[tid] = idx[nb + tid];
    __syncthreads();
#pragma unroll 4
    for (int l = 0; l < 64; ++l) {
        T[tid][l] = emb[(size_t)lidx[l] * EMB_DIM + tid];
    }
    __syncthreads();
    double sse = 0.0;
    const int lo = tid & 63;
    const int ch = tid >> 6;
    for (int it = 0; it < 64; ++it) {
        const int c = (it << 2) + ch;
        const size_t g = (size_t)b * (EMB_DIM * SEQ) + (size_t)c * SEQ + l0 + lo;
        const float q = T[c][lo];
        const float x = in[g];
        qout[g] = q;
        const float d = q - x;
        sse += (double)d * (double)d;
    }
    rd[tid] = sse;
    __syncthreads();
    for (int s = 128; s > 0; s >>= 1) {
        if (tid < s) rd[tid] += rd[tid + s];
        __syncthreads();
    }
    if (tid == 0) ssep[bid] = rd[0];
}

// one-hot encodings: float4 stores, every element rewritten every call
__global__ __launch_bounds__(256) void k_enc(const int* __restrict__ idx, float* __restrict__ enc) {
    const int gid = blockIdx.x * 256 + threadIdx.x;   // 16777216 threads
    const int n = gid >> 8;
    const int kk = (gid & 255) << 2;
    const int e = idx[n];
    float4 v;
    v.x = (e == kk) ? 1.0f : 0.0f;
    v.y = (e == kk + 1) ? 1.0f : 0.0f;
    v.z = (e == kk + 2) ? 1.0f : 0.0f;
    v.w = (e == kk + 3) ? 1.0f : 0.0f;
    *(float4*)(enc + (size_t)n * NUM_EMB + kk) = v;
}

__global__ __launch_bounds__(256) void k_final(const double* __restrict__ ssep,
                                               const int* __restrict__ counts,
                                               float* __restrict__ out)
{
    __shared__ double rd[256];
    const int tid = threadIdx.x;
    double s = 0.0;
    for (int i = tid; i < 1024; i += 256) s += ssep[i];
    rd[tid] = s;
    __syncthreads();
    for (int st = 128; st > 0; st >>= 1) {
        if (tid < st) rd[tid] += rd[tid + st];
        __syncthreads();
    }
    const double total = rd[0];
    __syncthreads();
    double pl = 0.0;
    for (int k = tid; k < 1024; k += 256) {
        const double p = (double)counts[k] * (1.0 / 65536.0);
        pl += p * log(p + 1e-10);
    }
    rd[tid] = pl;
    __syncthreads();
    for (int st = 128; st > 0; st >>= 1) {
        if (tid < st) rd[tid] += rd[tid + st];
        __syncthreads();
    }
    if (tid == 0) {
        out[0] = (float)(1.25 * (total * (1.0 / 16777216.0)));
        out[PERP_OFF] = (float)exp(-rd[0]);
    }
}

extern "C" void kernel_launch(void* const* d_in, const int* in_sizes, int n_in,
                              void* d_out, int out_size, void* d_ws, size_t ws_size,
                              hipStream_t stream)
{
    const float* in  = (const float*)d_in[0];
    const float* emb = (const float*)d_in[1];
    float* out = (float*)d_out;
    char* ws = (char*)d_ws;
    int*      idx    = (int*)(ws + WS_IDX);
    float*    e2     = (float*)(ws + WS_E2);
    int*      counts = (int*)(ws + WS_COUNTS);
    double*   ssep   = (double*)(ws + WS_SSE);
    unsigned* emx    = (unsigned*)(ws + WS_EMX);

    // bf16 E image carved from the encodings output region (overwritten by k_enc)
    char* ebf = (char*)d_out + ((size_t)ENC_OFF * 4 + 8);   // 16B-aligned, 512 KB

    k_zero<<<dim3(5), dim3(256), 0, stream>>>(counts, emx);
    k_e2<<<dim3(4), dim3(256), 0, stream>>>(emb, e2, emx);
    k_prep_e<<<dim3(32), dim3(256), 0, stream>>>(emb, ebf);
    k_dist<<<dim3(1024), dim3(256), 0, stream>>>(in, ebf, emb, e2, emx, idx, counts);
    k_quant<<<dim3(1024), dim3(256), 0, stream>>>(in, emb, idx, out + Q_OFF, ssep);
    k_enc<<<dim3(65536), dim3(256), 0, stream>>>(idx, out + ENC_OFF);
    k_final<<<dim3(1), dim3(256), 0, stream>>>(ssep, counts, out);
}